// Round 4
// baseline (254.636 us; speedup 1.0000x reference)
//
#include <hip/hip_runtime.h>
#include <hip/hip_bf16.h>
#include <stdint.h>

typedef __attribute__((ext_vector_type(4))) float f32x4;
typedef __attribute__((ext_vector_type(8))) short s16x8;

__device__ __forceinline__ unsigned int pack_bf2(float lo, float hi) {
  union { __hip_bfloat162 h; unsigned int u; } cv;
  cv.h = __float22bfloat162_rn(float2{lo, hi});
  return cv.u;
}
__device__ __forceinline__ float bflo(unsigned int w) { return __uint_as_float(w << 16); }
__device__ __forceinline__ float bfhi(unsigned int w) { return __uint_as_float(w & 0xFFFF0000u); }

union FragU { uint4 u; s16x8 s; };

// Convert W_qk (16384 f32) and W_v (16384 f32) to bf16 in workspace.
__global__ void __launch_bounds__(256) prep_weights(const float* __restrict__ Wqk,
                                                    const float* __restrict__ Wv,
                                                    uint16_t* __restrict__ wsqk,
                                                    uint16_t* __restrict__ wsv) {
  int i = blockIdx.x * 256 + threadIdx.x;
  if (i < 16384) {
    union { __hip_bfloat16 h; uint16_t u; } c; c.h = __float2bfloat16(Wqk[i]);
    wsqk[i] = c.u;
  } else if (i < 32768) {
    int j = i - 16384;
    union { __hip_bfloat16 h; uint16_t u; } c; c.h = __float2bfloat16(Wv[j]);
    wsv[j] = c.u;
  }
}

// One WG = 4 waves; wave w owns n = n0 + w. 3 barriers per WG.
// P relayout is a WAVE-PRIVATE LDS round-trip (no barrier; proven pattern from R1).
__global__ void __launch_bounds__(256, 4) attn_kernel(
    const float* __restrict__ X,          // (16,128,1024,16) f32
    const float* __restrict__ bqk,        // (128) f32
    const float* __restrict__ bv,         // (128) f32
    const unsigned int* __restrict__ wqk, // 128x128 bf16 as 8192 words
    const unsigned int* __restrict__ wv,  // 128x128 bf16 as 8192 words
    float* __restrict__ out)              // (16,1024,128) f32
{
  __shared__ unsigned int sXt[64 * 68];   // Xt[j][c-pair] bf16, row stride 68 words
  __shared__ unsigned int sP[64 * 68];    // staging [c][j-pair] first; then Pt[j][o-pair]; then Y in row w*16
  __shared__ float sa[4][16];
  __shared__ float sS[4];

  const int t    = threadIdx.x;
  const int lane = t & 63;
  const int w    = t >> 6;      // wave 0..3 -> local n
  const int nn   = lane & 15;
  const int quad = lane >> 4;

  const int b  = blockIdx.x >> 8;
  const int n0 = (blockIdx.x & 255) << 2;

  // ---- Stage A: global fp32 -> sP natural bf16 [c][j], row stride 32 words ----
  {
    const int j4 = t & 15;      // float4 index within 64-col row
    const int cb = t >> 4;
    #pragma unroll
    for (int it = 0; it < 8; ++it) {
      const int c = cb + it * 16;
      const float4 v = *reinterpret_cast<const float4*>(
          X + ((size_t)(b * 128 + c) * 1024 + n0) * 16 + j4 * 4);
      uint2 pk;
      pk.x = pack_bf2(v.x, v.y);
      pk.y = pack_bf2(v.z, v.w);
      *reinterpret_cast<uint2*>(&sP[c * 32 + j4 * 2]) = pk;
    }
  }
  __syncthreads();

  // ---- Stage B: transpose -> sXt[j][c] (bank-even via ch rotation) ----
  {
    const int jp = t & 31;      // j pair (2jp, 2jp+1)
    const int cg = t >> 5;      // 0..7
    #pragma unroll
    for (int s = 0; s < 2; ++s) {
      const int ch = (cg + 8 * s + jp) & 15;   // 8-c chunk index
      unsigned int wd[8];
      #pragma unroll
      for (int i = 0; i < 8; ++i) wd[i] = sP[(ch * 8 + i) * 32 + jp];
      uint4 lo, hi;
      lo.x = (wd[0] & 0xFFFFu) | (wd[1] << 16);
      lo.y = (wd[2] & 0xFFFFu) | (wd[3] << 16);
      lo.z = (wd[4] & 0xFFFFu) | (wd[5] << 16);
      lo.w = (wd[6] & 0xFFFFu) | (wd[7] << 16);
      hi.x = (wd[0] >> 16) | (wd[1] & 0xFFFF0000u);
      hi.y = (wd[2] >> 16) | (wd[3] & 0xFFFF0000u);
      hi.z = (wd[4] >> 16) | (wd[5] & 0xFFFF0000u);
      hi.w = (wd[6] >> 16) | (wd[7] & 0xFFFF0000u);
      *reinterpret_cast<uint4*>(&sXt[(2 * jp) * 68 + ch * 4]) = lo;
      *reinterpret_cast<uint4*>(&sXt[(2 * jp + 1) * 68 + ch * 4]) = hi;
    }
  }
  __syncthreads();
  // ===== From here to the final barrier: everything is wave-private (n = n0+w) =====

  // ---- Stage 1: P_n = Wqk @ X_n + bqk, full 128x16 per wave; acc[mt]: rows o=mt*16+quad*4+r, col k=nn ----
  f32x4 acc[8];
  {
    #pragma unroll
    for (int mt = 0; mt < 8; ++mt) {
      const float4 bq = *reinterpret_cast<const float4*>(bqk + mt * 16 + quad * 4);
      acc[mt][0] = bq.x; acc[mt][1] = bq.y; acc[mt][2] = bq.z; acc[mt][3] = bq.w;
    }
    #pragma unroll
    for (int ks = 0; ks < 4; ++ks) {
      FragU bfr;
      bfr.u = *reinterpret_cast<const uint4*>(&sXt[(w * 16 + nn) * 68 + ks * 16 + quad * 4]);
      #pragma unroll
      for (int mt = 0; mt < 8; ++mt) {
        FragU af;
        af.u = *reinterpret_cast<const uint4*>(wqk + (mt * 16 + nn) * 64 + ks * 16 + quad * 4);
        acc[mt] = __builtin_amdgcn_mfma_f32_16x16x32_bf16(af.s, bfr.s, acc[mt], 0, 0, 0);
      }
    }
  }

  // ---- Stage 2a: P -> wave-private LDS rows Pt[j=w*16+nn][o-pair] (no barrier needed) ----
  {
    #pragma unroll
    for (int mt = 0; mt < 8; ++mt) {
      uint2 pr;
      pr.x = pack_bf2(acc[mt][0], acc[mt][1]);
      pr.y = pack_bf2(acc[mt][2], acc[mt][3]);
      *reinterpret_cast<uint2*>(&sP[(w * 16 + nn) * 68 + mt * 8 + quad * 2]) = pr;
    }
  }

  // ---- Stage 2b: E = Q^T K (frags re-read with stage-1's indexing convention), softmax, col 0 ----
  float aq[16];
  float Ssum;
  {
    f32x4 e = {0.f, 0.f, 0.f, 0.f};
    #pragma unroll
    for (int ks = 0; ks < 2; ++ks) {
      FragU qa, kb;
      qa.u = *reinterpret_cast<const uint4*>(&sP[(w * 16 + nn) * 68 + ks * 16 + quad * 4]);        // Q: o 0..63
      kb.u = *reinterpret_cast<const uint4*>(&sP[(w * 16 + nn) * 68 + 32 + ks * 16 + quad * 4]);   // K: o 64..127
      e = __builtin_amdgcn_mfma_f32_16x16x32_bf16(qa.s, kb.s, e, 0, 0, 0);
    }
    // E: row qi = quad*4+r, col ki = nn. Softmax over ki (lanes with same quad), take ki=0.
    #pragma unroll
    for (int r = 0; r < 4; ++r) {
      float l = e[r] * 0.125f;             // / sqrt(64)
      float mx = l;
      mx = fmaxf(mx, __shfl_xor(mx, 1));
      mx = fmaxf(mx, __shfl_xor(mx, 2));
      mx = fmaxf(mx, __shfl_xor(mx, 4));
      mx = fmaxf(mx, __shfl_xor(mx, 8));
      float pe = __expf(l - mx);
      float ss = pe;
      ss += __shfl_xor(ss, 1);
      ss += __shfl_xor(ss, 2);
      ss += __shfl_xor(ss, 4);
      ss += __shfl_xor(ss, 8);
      if (nn == 0) sa[w][quad * 4 + r] = pe / ss;   // attention[qi][0]
    }
    Ssum = 0.f;
    #pragma unroll
    for (int k = 0; k < 16; ++k) { aq[k] = sa[w][k]; Ssum += aq[k]; }   // wave-private LDS readback
  }

  // ---- Stage Y: y_n[c] = sum_k aq[k] * X[c][n][k]; store into wave's own dead P region ----
  unsigned int* sYw = &sP[w * 16 * 68];   // row w*16, words 0..63
  {
    float y0 = 0.f, y1 = 0.f;
    #pragma unroll
    for (int k = 0; k < 16; ++k) {
      const unsigned int xw = sXt[(w * 16 + k) * 68 + lane];
      y0 += aq[k] * bflo(xw);
      y1 += aq[k] * bfhi(xw);
    }
    sYw[lane] = pack_bf2(y0, y1);
    if (lane == 0) sS[w] = Ssum;
  }
  __syncthreads();

  // ---- Stage 3: Out = Wv @ Y + bv * S (4 n's jointly; wave w -> c-tiles 2w, 2w+1) ----
  {
    #pragma unroll
    for (int i = 0; i < 2; ++i) {
      const int ct = w * 2 + i;
      f32x4 z = {0.f, 0.f, 0.f, 0.f};
      #pragma unroll
      for (int ks = 0; ks < 4; ++ks) {
        FragU av2, by;
        av2.u = *reinterpret_cast<const uint4*>(wv + (ct * 16 + nn) * 64 + ks * 16 + quad * 4);
        by.u  = *reinterpret_cast<const uint4*>(&sP[(nn & 3) * 16 * 68 + ks * 16 + quad * 4]);  // Y[n=nn&3][c]
        z = __builtin_amdgcn_mfma_f32_16x16x32_bf16(av2.s, by.s, z, 0, 0, 0);
      }
      if (nn < 4) {
        const float4 bvv = *reinterpret_cast<const float4*>(bv + ct * 16 + quad * 4);
        const float S = sS[nn];
        float4 o4;
        o4.x = z[0] + bvv.x * S;
        o4.y = z[1] + bvv.y * S;
        o4.z = z[2] + bvv.z * S;
        o4.w = z[3] + bvv.w * S;
        *reinterpret_cast<float4*>(out + (size_t)(b * 1024 + n0 + nn) * 128 + ct * 16 + quad * 4) = o4;
      }
    }
  }
}

extern "C" void kernel_launch(void* const* d_in, const int* in_sizes, int n_in,
                              void* d_out, int out_size, void* d_ws, size_t ws_size,
                              hipStream_t stream) {
  (void)in_sizes; (void)n_in; (void)out_size; (void)ws_size;
  const float* X   = (const float*)d_in[0];
  const float* Wqk = (const float*)d_in[1];
  const float* bqk = (const float*)d_in[2];
  const float* Wv  = (const float*)d_in[3];
  const float* bv  = (const float*)d_in[4];
  // d_in[5] = qk_dim (=64), compile-time constant here.

  uint16_t* wsqk = (uint16_t*)d_ws;           // 32 KB
  uint16_t* wsv  = wsqk + 16384;              // 32 KB

  prep_weights<<<128, 256, 0, stream>>>(Wqk, Wv, wsqk, wsv);
  attn_kernel<<<4096, 256, 0, stream>>>(X, bqk, bv,
                                        (const unsigned int*)wsqk,
                                        (const unsigned int*)wsv,
                                        (float*)d_out);
}

// Round 5
// 253.632 us; speedup vs baseline: 1.0040x; 1.0040x over previous
//
#include <hip/hip_runtime.h>
#include <hip/hip_bf16.h>
#include <stdint.h>

typedef __attribute__((ext_vector_type(4))) float f32x4;
typedef __attribute__((ext_vector_type(8))) short s16x8;

__device__ __forceinline__ unsigned int pack_bf2(float lo, float hi) {
  union { __hip_bfloat162 h; unsigned int u; } cv;
  cv.h = __float22bfloat162_rn(float2{lo, hi});
  return cv.u;
}
__device__ __forceinline__ float bflo(unsigned int w) { return __uint_as_float(w << 16); }
__device__ __forceinline__ float bfhi(unsigned int w) { return __uint_as_float(w & 0xFFFF0000u); }

union FragU { uint4 u; s16x8 s; };

// Convert W_qk (16384 f32) and W_v (16384 f32) to bf16 in workspace.
__global__ void __launch_bounds__(256) prep_weights(const float* __restrict__ Wqk,
                                                    const float* __restrict__ Wv,
                                                    uint16_t* __restrict__ wsqk,
                                                    uint16_t* __restrict__ wsv) {
  int i = blockIdx.x * 256 + threadIdx.x;
  if (i < 16384) {
    union { __hip_bfloat16 h; uint16_t u; } c; c.h = __float2bfloat16(Wqk[i]);
    wsqk[i] = c.u;
  } else if (i < 32768) {
    int j = i - 16384;
    union { __hip_bfloat16 h; uint16_t u; } c; c.h = __float2bfloat16(Wv[j]);
    wsv[j] = c.u;
  }
}

// One WG = 4 waves; wave w owns n = n0 + w. ONE barrier per WG.
// B-frags (X^T) are loaded straight from global (4 lines/instr coalescing),
// so there is no staging/transpose at all. Wave-private LDS round-trips
// (P relayout, sa broadcast, Y) need no barrier; only stage 3 (cross-wave Y) does.
__global__ void __launch_bounds__(256, 4) attn_kernel(
    const float* __restrict__ X,          // (16,128,1024,16) f32
    const float* __restrict__ bqk,        // (128) f32
    const float* __restrict__ bv,         // (128) f32
    const unsigned int* __restrict__ wqk, // 128x128 bf16 as 8192 words
    const unsigned int* __restrict__ wv,  // 128x128 bf16 as 8192 words
    float* __restrict__ out)              // (16,1024,128) f32
{
  __shared__ unsigned int sXt[64 * 68];   // Xt[j][c-pair] bf16, row stride 68 words (wave-private rows)
  __shared__ unsigned int sP[64 * 68];    // Pt[j][o-pair]; row w*16 later reused for Y
  __shared__ float sa[4][16];
  __shared__ float sS[4];

  const int t    = threadIdx.x;
  const int lane = t & 63;
  const int w    = t >> 6;      // wave 0..3 -> local n
  const int nn   = lane & 15;
  const int quad = lane >> 4;

  const int b  = blockIdx.x >> 8;
  const int n0 = (blockIdx.x & 255) << 2;
  const int n  = n0 + w;

  // ---- Stage L: load X^T B-frags directly from global; also dump to sXt (wave-private) ----
  // Lane (nn,quad), ks: needs X[c][n][nn] for c = ks*32 + quad*8 + i, i=0..7.
  // Per instruction: 16 nn-lanes = one contiguous 64B line, 4 quads = 4 lines. Coalesced.
  FragU xf[4];
  {
    const float* __restrict__ xb = X + (size_t)b * (128 * 1024 * 16) + n * 16 + nn;
    #pragma unroll
    for (int ks = 0; ks < 4; ++ks) {
      const int c0 = ks * 32 + quad * 8;
      float v[8];
      #pragma unroll
      for (int i = 0; i < 8; ++i)
        v[i] = xb[(size_t)(c0 + i) * (1024 * 16)];
      xf[ks].u.x = pack_bf2(v[0], v[1]);
      xf[ks].u.y = pack_bf2(v[2], v[3]);
      xf[ks].u.z = pack_bf2(v[4], v[5]);
      xf[ks].u.w = pack_bf2(v[6], v[7]);
      *reinterpret_cast<uint4*>(&sXt[(w * 16 + nn) * 68 + ks * 16 + quad * 4]) = xf[ks].u;
    }
  }

  // ---- Stage 1: P_n = Wqk @ X_n + bqk; acc[mt]: rows o=mt*16+quad*4+r, col k=nn ----
  f32x4 acc[8];
  {
    #pragma unroll
    for (int mt = 0; mt < 8; ++mt) {
      const float4 bq = *reinterpret_cast<const float4*>(bqk + mt * 16 + quad * 4);
      acc[mt][0] = bq.x; acc[mt][1] = bq.y; acc[mt][2] = bq.z; acc[mt][3] = bq.w;
    }
    #pragma unroll
    for (int ks = 0; ks < 4; ++ks) {
      #pragma unroll
      for (int mt = 0; mt < 8; ++mt) {
        FragU af;
        af.u = *reinterpret_cast<const uint4*>(wqk + (mt * 16 + nn) * 64 + ks * 16 + quad * 4);
        acc[mt] = __builtin_amdgcn_mfma_f32_16x16x32_bf16(af.s, xf[ks].s, acc[mt], 0, 0, 0);
      }
    }
  }

  // ---- Stage 2a: P -> wave-private LDS rows Pt[j=w*16+nn][o-pair] (no barrier needed) ----
  {
    #pragma unroll
    for (int mt = 0; mt < 8; ++mt) {
      uint2 pr;
      pr.x = pack_bf2(acc[mt][0], acc[mt][1]);
      pr.y = pack_bf2(acc[mt][2], acc[mt][3]);
      *reinterpret_cast<uint2*>(&sP[(w * 16 + nn) * 68 + mt * 8 + quad * 2]) = pr;
    }
  }

  // ---- Stage 2b: E = Q^T K (frags re-read with stage-1's indexing convention), softmax, col 0 ----
  float aq[16];
  float Ssum;
  {
    f32x4 e = {0.f, 0.f, 0.f, 0.f};
    #pragma unroll
    for (int ks = 0; ks < 2; ++ks) {
      FragU qa, kb;
      qa.u = *reinterpret_cast<const uint4*>(&sP[(w * 16 + nn) * 68 + ks * 16 + quad * 4]);        // Q: o 0..63
      kb.u = *reinterpret_cast<const uint4*>(&sP[(w * 16 + nn) * 68 + 32 + ks * 16 + quad * 4]);   // K: o 64..127
      e = __builtin_amdgcn_mfma_f32_16x16x32_bf16(qa.s, kb.s, e, 0, 0, 0);
    }
    // E: row qi = quad*4+r, col ki = nn. Softmax over ki (lanes with same quad), take ki=0.
    #pragma unroll
    for (int r = 0; r < 4; ++r) {
      float l = e[r] * 0.125f;             // / sqrt(64)
      float mx = l;
      mx = fmaxf(mx, __shfl_xor(mx, 1));
      mx = fmaxf(mx, __shfl_xor(mx, 2));
      mx = fmaxf(mx, __shfl_xor(mx, 4));
      mx = fmaxf(mx, __shfl_xor(mx, 8));
      float pe = __expf(l - mx);
      float ss = pe;
      ss += __shfl_xor(ss, 1);
      ss += __shfl_xor(ss, 2);
      ss += __shfl_xor(ss, 4);
      ss += __shfl_xor(ss, 8);
      if (nn == 0) sa[w][quad * 4 + r] = pe / ss;   // attention[qi][0]
    }
    Ssum = 0.f;
    #pragma unroll
    for (int k = 0; k < 16; ++k) { aq[k] = sa[w][k]; Ssum += aq[k]; }   // wave-private LDS readback
  }

  // ---- Stage Y: y_n[c] = sum_k aq[k] * X[c][n][k]; store into wave's own dead P region ----
  unsigned int* sYw = &sP[w * 16 * 68];   // row w*16, words 0..63
  {
    float y0 = 0.f, y1 = 0.f;
    #pragma unroll
    for (int k = 0; k < 16; ++k) {
      const unsigned int xw = sXt[(w * 16 + k) * 68 + lane];
      y0 += aq[k] * bflo(xw);
      y1 += aq[k] * bfhi(xw);
    }
    sYw[lane] = pack_bf2(y0, y1);
    if (lane == 0) sS[w] = Ssum;
  }
  __syncthreads();

  // ---- Stage 3: Out = Wv @ Y + bv * S (4 n's jointly; wave w -> c-tiles 2w, 2w+1) ----
  {
    #pragma unroll
    for (int i = 0; i < 2; ++i) {
      const int ct = w * 2 + i;
      f32x4 z = {0.f, 0.f, 0.f, 0.f};
      #pragma unroll
      for (int ks = 0; ks < 4; ++ks) {
        FragU av2, by;
        av2.u = *reinterpret_cast<const uint4*>(wv + (ct * 16 + nn) * 64 + ks * 16 + quad * 4);
        by.u  = *reinterpret_cast<const uint4*>(&sP[(nn & 3) * 16 * 68 + ks * 16 + quad * 4]);  // Y[n=nn&3][c]
        z = __builtin_amdgcn_mfma_f32_16x16x32_bf16(av2.s, by.s, z, 0, 0, 0);
      }
      if (nn < 4) {
        const float4 bvv = *reinterpret_cast<const float4*>(bv + ct * 16 + quad * 4);
        const float S = sS[nn];
        float4 o4;
        o4.x = z[0] + bvv.x * S;
        o4.y = z[1] + bvv.y * S;
        o4.z = z[2] + bvv.z * S;
        o4.w = z[3] + bvv.w * S;
        *reinterpret_cast<float4*>(out + (size_t)(b * 1024 + n0 + nn) * 128 + ct * 16 + quad * 4) = o4;
      }
    }
  }
}

extern "C" void kernel_launch(void* const* d_in, const int* in_sizes, int n_in,
                              void* d_out, int out_size, void* d_ws, size_t ws_size,
                              hipStream_t stream) {
  (void)in_sizes; (void)n_in; (void)out_size; (void)ws_size;
  const float* X   = (const float*)d_in[0];
  const float* Wqk = (const float*)d_in[1];
  const float* bqk = (const float*)d_in[2];
  const float* Wv  = (const float*)d_in[3];
  const float* bv  = (const float*)d_in[4];
  // d_in[5] = qk_dim (=64), compile-time constant here.

  uint16_t* wsqk = (uint16_t*)d_ws;           // 32 KB
  uint16_t* wsv  = wsqk + 16384;              // 32 KB

  prep_weights<<<128, 256, 0, stream>>>(Wqk, Wv, wsqk, wsv);
  attn_kernel<<<4096, 256, 0, stream>>>(X, bqk, bv,
                                        (const unsigned int*)wsqk,
                                        (const unsigned int*)wsv,
                                        (float*)d_out);
}

// Round 6
// 222.761 us; speedup vs baseline: 1.1431x; 1.1386x over previous
//
#include <hip/hip_runtime.h>
#include <hip/hip_bf16.h>
#include <stdint.h>

typedef __attribute__((ext_vector_type(4))) float f32x4;
typedef __attribute__((ext_vector_type(8))) short s16x8;

__device__ __forceinline__ unsigned int pack_bf2(float lo, float hi) {
  union { __hip_bfloat162 h; unsigned int u; } cv;
  cv.h = __float22bfloat162_rn(float2{lo, hi});
  return cv.u;
}
__device__ __forceinline__ float bflo(unsigned int w) { return __uint_as_float(w << 16); }
__device__ __forceinline__ float bfhi(unsigned int w) { return __uint_as_float(w & 0xFFFF0000u); }

union FragU { uint4 u; s16x8 s; };

// Convert W_qk (16384 f32) and W_v (16384 f32) to bf16 in workspace.
__global__ void __launch_bounds__(256) prep_weights(const float* __restrict__ Wqk,
                                                    const float* __restrict__ Wv,
                                                    uint16_t* __restrict__ wsqk,
                                                    uint16_t* __restrict__ wsv) {
  int i = blockIdx.x * 256 + threadIdx.x;
  if (i < 16384) {
    union { __hip_bfloat16 h; uint16_t u; } c; c.h = __float2bfloat16(Wqk[i]);
    wsqk[i] = c.u;
  } else if (i < 32768) {
    int j = i - 16384;
    union { __hip_bfloat16 h; uint16_t u; } c; c.h = __float2bfloat16(Wv[j]);
    wsv[j] = c.u;
  }
}

// One WG = 4 waves, 4 n's. Stage-1 split is TRANSPOSED vs R5: wave w computes
// P rows mt=2w..2w+1 for ALL 4 n's, so it needs only 8 wqk A-frags (32 VGPRs,
// preloaded before the MFMA loop -> no load->MFMA serial chain) and wqk is
// read once per WG instead of once per wave. 3 barriers.
__global__ void __launch_bounds__(256, 4) attn_kernel(
    const float* __restrict__ X,          // (16,128,1024,16) f32
    const float* __restrict__ bqk,        // (128) f32
    const float* __restrict__ bv,         // (128) f32
    const unsigned int* __restrict__ wqk, // 128x128 bf16 as 8192 words
    const unsigned int* __restrict__ wv,  // 128x128 bf16 as 8192 words
    float* __restrict__ out)              // (16,1024,128) f32
{
  __shared__ unsigned int sXt[64 * 68];   // Xt[n*16+k][c-pair] bf16, row stride 68 words
  __shared__ unsigned int sP[64 * 68];    // Pt[n*16+k][o-pair]; row n*16 later reused for Y
  __shared__ float sa[4][16];
  __shared__ float sS[4];

  const int t    = threadIdx.x;
  const int lane = t & 63;
  const int w    = t >> 6;      // wave 0..3
  const int nn   = lane & 15;
  const int quad = lane >> 4;

  const int b  = blockIdx.x >> 8;
  const int n0 = (blockIdx.x & 255) << 2;

  // ---- Stage L: wave w loads X^T for n = n0+w straight from global -> sXt rows w*16+k ----
  // Lane (nn,quad), ks: X[c][n][nn] for c = ks*32+quad*8+i. 16 nn-lanes = one 64B line.
  {
    const float* __restrict__ xb = X + (size_t)b * (128 * 1024 * 16) + (n0 + w) * 16 + nn;
    #pragma unroll
    for (int ks = 0; ks < 4; ++ks) {
      const int c0 = ks * 32 + quad * 8;
      float v[8];
      #pragma unroll
      for (int i = 0; i < 8; ++i)
        v[i] = xb[(size_t)(c0 + i) * (1024 * 16)];
      uint4 xw;
      xw.x = pack_bf2(v[0], v[1]);
      xw.y = pack_bf2(v[2], v[3]);
      xw.z = pack_bf2(v[4], v[5]);
      xw.w = pack_bf2(v[6], v[7]);
      *reinterpret_cast<uint4*>(&sXt[(w * 16 + nn) * 68 + ks * 16 + quad * 4]) = xw;
    }
  }
  __syncthreads();   // barrier 1: sXt complete

  // ---- Stage 1: P rows mt=2w+i (i=0,1) for all n; A-frags PRELOADED (8 frags, 32 VGPRs) ----
  f32x4 acc[2][4];   // [i][n]
  {
    FragU af[2][4];  // [i][ks] - preload all wqk frags this wave ever needs
    #pragma unroll
    for (int i = 0; i < 2; ++i)
      #pragma unroll
      for (int ks = 0; ks < 4; ++ks)
        af[i][ks].u = *reinterpret_cast<const uint4*>(
            wqk + ((2 * w + i) * 16 + nn) * 64 + ks * 16 + quad * 4);
    #pragma unroll
    for (int i = 0; i < 2; ++i) {
      const float4 bq = *reinterpret_cast<const float4*>(bqk + (2 * w + i) * 16 + quad * 4);
      #pragma unroll
      for (int n = 0; n < 4; ++n) {
        acc[i][n][0] = bq.x; acc[i][n][1] = bq.y;
        acc[i][n][2] = bq.z; acc[i][n][3] = bq.w;
      }
    }
    #pragma unroll
    for (int ks = 0; ks < 4; ++ks) {
      FragU bf[4];
      #pragma unroll
      for (int n = 0; n < 4; ++n)
        bf[n].u = *reinterpret_cast<const uint4*>(&sXt[(n * 16 + nn) * 68 + ks * 16 + quad * 4]);
      #pragma unroll
      for (int i = 0; i < 2; ++i)
        #pragma unroll
        for (int n = 0; n < 4; ++n)
          acc[i][n] = __builtin_amdgcn_mfma_f32_16x16x32_bf16(af[i][ks].s, bf[n].s, acc[i][n], 0, 0, 0);
    }
  }

  // ---- Stage 2a: P -> sP rows n*16+nn, o-pairs (2w+i)*8 + quad*2 ----
  {
    #pragma unroll
    for (int i = 0; i < 2; ++i)
      #pragma unroll
      for (int n = 0; n < 4; ++n) {
        uint2 pr;
        pr.x = pack_bf2(acc[i][n][0], acc[i][n][1]);
        pr.y = pack_bf2(acc[i][n][2], acc[i][n][3]);
        *reinterpret_cast<uint2*>(&sP[(n * 16 + nn) * 68 + (2 * w + i) * 8 + quad * 2]) = pr;
      }
  }
  __syncthreads();   // barrier 2: sP complete (P rows come from all waves)

  // ---- Stage 2b: E = Q^T K for n=w (frags re-read with stage-1 indexing), softmax, col 0 ----
  float aq[16];
  float Ssum;
  {
    f32x4 e = {0.f, 0.f, 0.f, 0.f};
    #pragma unroll
    for (int ks = 0; ks < 2; ++ks) {
      FragU qa, kb;
      qa.u = *reinterpret_cast<const uint4*>(&sP[(w * 16 + nn) * 68 + ks * 16 + quad * 4]);        // Q: o 0..63
      kb.u = *reinterpret_cast<const uint4*>(&sP[(w * 16 + nn) * 68 + 32 + ks * 16 + quad * 4]);   // K: o 64..127
      e = __builtin_amdgcn_mfma_f32_16x16x32_bf16(qa.s, kb.s, e, 0, 0, 0);
    }
    // E: row qi = quad*4+r, col ki = nn. Softmax over ki (lanes with same quad), take ki=0.
    #pragma unroll
    for (int r = 0; r < 4; ++r) {
      float l = e[r] * 0.125f;             // / sqrt(64)
      float mx = l;
      mx = fmaxf(mx, __shfl_xor(mx, 1));
      mx = fmaxf(mx, __shfl_xor(mx, 2));
      mx = fmaxf(mx, __shfl_xor(mx, 4));
      mx = fmaxf(mx, __shfl_xor(mx, 8));
      float pe = __expf(l - mx);
      float ss = pe;
      ss += __shfl_xor(ss, 1);
      ss += __shfl_xor(ss, 2);
      ss += __shfl_xor(ss, 4);
      ss += __shfl_xor(ss, 8);
      if (nn == 0) sa[w][quad * 4 + r] = pe / ss;   // attention[qi][0]
    }
    Ssum = 0.f;
    #pragma unroll
    for (int k = 0; k < 16; ++k) { aq[k] = sa[w][k]; Ssum += aq[k]; }   // wave-private LDS readback
  }

  // ---- Stage Y: y_n[c] = sum_k aq[k] * X[c][n][k] for n=w; store into own dead P row ----
  unsigned int* sYw = &sP[w * 16 * 68];   // row w*16, words 0..63
  {
    float y0 = 0.f, y1 = 0.f;
    #pragma unroll
    for (int k = 0; k < 16; ++k) {
      const unsigned int xw = sXt[(w * 16 + k) * 68 + lane];
      y0 += aq[k] * bflo(xw);
      y1 += aq[k] * bfhi(xw);
    }
    sYw[lane] = pack_bf2(y0, y1);
    if (lane == 0) sS[w] = Ssum;
  }
  __syncthreads();   // barrier 3: Y complete

  // ---- Stage 3: Out = Wv @ Y + bv * S (wave w -> c-tiles 2w, 2w+1) ----
  {
    #pragma unroll
    for (int i = 0; i < 2; ++i) {
      const int ct = w * 2 + i;
      f32x4 z = {0.f, 0.f, 0.f, 0.f};
      #pragma unroll
      for (int ks = 0; ks < 4; ++ks) {
        FragU av2, by;
        av2.u = *reinterpret_cast<const uint4*>(wv + (ct * 16 + nn) * 64 + ks * 16 + quad * 4);
        by.u  = *reinterpret_cast<const uint4*>(&sP[(nn & 3) * 16 * 68 + ks * 16 + quad * 4]);  // Y[n=nn&3][c]
        z = __builtin_amdgcn_mfma_f32_16x16x32_bf16(av2.s, by.s, z, 0, 0, 0);
      }
      if (nn < 4) {
        const float4 bvv = *reinterpret_cast<const float4*>(bv + ct * 16 + quad * 4);
        const float S = sS[nn];
        float4 o4;
        o4.x = z[0] + bvv.x * S;
        o4.y = z[1] + bvv.y * S;
        o4.z = z[2] + bvv.z * S;
        o4.w = z[3] + bvv.w * S;
        *reinterpret_cast<float4*>(out + (size_t)(b * 1024 + n0 + nn) * 128 + ct * 16 + quad * 4) = o4;
      }
    }
  }
}

extern "C" void kernel_launch(void* const* d_in, const int* in_sizes, int n_in,
                              void* d_out, int out_size, void* d_ws, size_t ws_size,
                              hipStream_t stream) {
  (void)in_sizes; (void)n_in; (void)out_size; (void)ws_size;
  const float* X   = (const float*)d_in[0];
  const float* Wqk = (const float*)d_in[1];
  const float* bqk = (const float*)d_in[2];
  const float* Wv  = (const float*)d_in[3];
  const float* bv  = (const float*)d_in[4];
  // d_in[5] = qk_dim (=64), compile-time constant here.

  uint16_t* wsqk = (uint16_t*)d_ws;           // 32 KB
  uint16_t* wsv  = wsqk + 16384;              // 32 KB

  prep_weights<<<128, 256, 0, stream>>>(Wqk, Wv, wsqk, wsv);
  attn_kernel<<<4096, 256, 0, stream>>>(X, bqk, bv,
                                        (const unsigned int*)wsqk,
                                        (const unsigned int*)wsv,
                                        (float*)d_out);
}